// Round 5
// baseline (481.446 us; speedup 1.0000x reference)
//
#include <hip/hip_runtime.h>
#include <math.h>

#define H 160
#define W 480
#define HW 76800
#define NPTS 120000

// ws layout (bytes):
//   winner0 @ 0        (76800*4)
//   winner1 @ 307200
//   winner2 @ 614400
//   accum   @ 921600   9 taps x [HW] floats = 2,764,800 B
//   Weff0   @ 3686400  (64*12*4)   layout [c][12]
//   Weff1   @ 3689472  (128*12*4)
//   bconst  @ 3695616  (9*4)
//   sa      @ 0        (aliases winner0; winners dead after fused_t9)
#define OFF_W1M 307200
#define OFF_W2M 614400
#define OFF_ACC 921600
#define OFF_WE0 3686400
#define OFF_WE1 3689472
#define OFF_BC  3695616

// blocks [0,7): weight folding; blocks [7,...): winner scatter
__global__ __launch_bounds__(256) void prep_and_scatter(
    const float* __restrict__ rw0, const float* __restrict__ rw1,
    const float* __restrict__ rb0, const float* __restrict__ rb1,
    const float* __restrict__ sbw,
    float* __restrict__ Weff0, float* __restrict__ Weff1, float* __restrict__ bconst,
    const int2* __restrict__ g0, const int2* __restrict__ g1, const int2* __restrict__ g2,
    int* __restrict__ w0, int* __restrict__ w1, int* __restrict__ w2) {
  if (blockIdx.x < 7) {
    int t = blockIdx.x * 256 + threadIdx.x;
    if (t < 576) {
      int jj = t / 64, k = t % 64;
      float s = 0.f;
      for (int c = 0; c < 256; ++c) s = fmaf(rw0[c * 64 + k], sbw[(256 + c) * 9 + jj], s);
      Weff0[k * 12 + jj] = s;
    } else if (t < 1728) {
      int tt = t - 576;
      int jj = tt / 128, k = tt % 128;
      float s = 0.f;
      for (int c = 0; c < 256; ++c) s = fmaf(rw1[c * 128 + k], sbw[(256 + c) * 9 + jj], s);
      Weff1[k * 12 + jj] = s;
    } else if (t < 1737) {
      int jj = t - 1728;
      float s = 0.f;
      for (int c = 0; c < 256; ++c) s = fmaf(rb0[c] + rb1[c], sbw[(256 + c) * 9 + jj], s);
      bconst[jj] = s;
    }
  } else {
    int j = (blockIdx.x - 7) * 256 + threadIdx.x;
    if (j >= NPTS) return;
    int2 c;
    c = g0[j];
    if ((unsigned)c.x < W && (unsigned)c.y < H) atomicMax(&w0[c.y * W + c.x], j);
    c = g1[j];
    if ((unsigned)c.x < W && (unsigned)c.y < H) atomicMax(&w1[c.y * W + c.x], j);
    c = g2[j];
    if ((unsigned)c.x < W && (unsigned)c.y < H) atomicMax(&w2[c.y * W + c.x], j);
  }
}

// One kernel, blockIdx.y units:
//   u=0: img c[0,128)*seg    (coalesced stream, atomicAdd 9 taps)
//   u=1: img c[128,256)*seg
//   u=2/3/4: voxel level 0/1/2, POINT-centric:
//     thread<->point j (j-ordered => winner-row reads are sequential-with-gaps,
//     not random: this is the address-stream fix after three depth fixes failed),
//     winner check = 1 dword into L2-resident map, 16-lane group per winner
//     (4 winners/wave via quad shfl-broadcast), 256B contiguous per group-chunk,
//     shfl_xor butterfly over 16 lanes, 9 atomicAdds into accum[9][HW].
__global__ __launch_bounds__(256) void fused_t9(
    const float* __restrict__ img, const float* __restrict__ seg,
    const float* __restrict__ vf0, const float* __restrict__ vf1,
    const float* __restrict__ vf2,
    const int2* __restrict__ g0, const int2* __restrict__ g1, const int2* __restrict__ g2,
    const int* __restrict__ w0m, const int* __restrict__ w1m, const int* __restrict__ w2m,
    const float* __restrict__ We0, const float* __restrict__ We1,
    const float* __restrict__ sbw, float* __restrict__ accum) {
  int u = blockIdx.y;
  if (u < 2) {
    int p = blockIdx.x * 256 + threadIdx.x;
    if (p >= HW) return;  // grid x sized for the vox units (469 > 300)
    const int c0 = u * 128;
    float acc[9];
#pragma unroll
    for (int j = 0; j < 9; ++j) acc[j] = 0.f;
    for (int cc = 0; cc < 128; cc += 16) {
      float v[16];
#pragma unroll
      for (int t = 0; t < 16; ++t) v[t] = img[(size_t)(c0 + cc + t) * HW + p];
      __builtin_amdgcn_sched_barrier(0);
#pragma unroll
      for (int t = 0; t < 16; ++t) {
        const float* wr = sbw + (c0 + cc + t) * 9;  // wave-uniform -> s_load
#pragma unroll
        for (int j = 0; j < 9; ++j) acc[j] = fmaf(v[t], wr[j], acc[j]);
      }
    }
    float s = seg[HW + p];
#pragma unroll
    for (int j = 0; j < 9; ++j) atomicAdd(&accum[(size_t)j * HW + p], acc[j] * s);
    return;
  }

  int lvl = u - 2;
  int jp = blockIdx.x * 256 + threadIdx.x;  // candidate point index
  int lane = threadIdx.x & 63;
  int wg = lane >> 4, sub = lane & 15;
  const int2* g = (lvl == 0) ? g0 : (lvl == 1) ? g1 : g2;
  const int* wm = (lvl == 0) ? w0m : (lvl == 1) ? w1m : w2m;

  int valid = 0, cell = 0;
  if (jp < NPTS) {
    int2 c = g[jp];
    if ((unsigned)c.x < W && (unsigned)c.y < H) {
      cell = c.y * W + c.x;
      valid = (wm[cell] == jp) ? 1 : 0;  // unique winner per (cell, level)
    }
  }
  unsigned long long m = __ballot(valid != 0);

  for (int s = 0; s < 16; ++s) {
    if (((m >> (s * 4)) & 0xFull) == 0) continue;  // wave-uniform skip
    int cl = s * 4 + wg;                 // candidate lane for my 16-lane group
    int vj = __shfl(jp, cl);
    int vcell = __shfl(cell, cl);
    int vvalid = __shfl(valid, cl);
    if (vvalid) {
      float acc[9];
#pragma unroll
      for (int j = 0; j < 9; ++j) acc[j] = 0.f;
      if (lvl == 0) {
        float4 v = ((const float4*)(vf0 + (size_t)vj * 64))[sub];
        const float* wc = We0 + sub * 4 * 12;
#pragma unroll
        for (int j = 0; j < 9; ++j) {
          acc[j] = fmaf(v.x, wc[j], acc[j]);
          acc[j] = fmaf(v.y, wc[12 + j], acc[j]);
          acc[j] = fmaf(v.z, wc[24 + j], acc[j]);
          acc[j] = fmaf(v.w, wc[36 + j], acc[j]);
        }
      } else if (lvl == 1) {
#pragma unroll
        for (int ch = 0; ch < 2; ++ch) {
          float4 v = ((const float4*)(vf1 + (size_t)vj * 128))[sub + 16 * ch];
          const float* wc = We1 + (sub * 4 + 64 * ch) * 12;
#pragma unroll
          for (int j = 0; j < 9; ++j) {
            acc[j] = fmaf(v.x, wc[j], acc[j]);
            acc[j] = fmaf(v.y, wc[12 + j], acc[j]);
            acc[j] = fmaf(v.z, wc[24 + j], acc[j]);
            acc[j] = fmaf(v.w, wc[36 + j], acc[j]);
          }
        }
      } else {
#pragma unroll
        for (int ch = 0; ch < 4; ++ch) {
          float4 v = ((const float4*)(vf2 + (size_t)vj * 256))[sub + 16 * ch];
          const float* wc = sbw + (256 + sub * 4 + 64 * ch) * 9;
#pragma unroll
          for (int j = 0; j < 9; ++j) {
            acc[j] = fmaf(v.x, wc[j], acc[j]);
            acc[j] = fmaf(v.y, wc[9 + j], acc[j]);
            acc[j] = fmaf(v.z, wc[18 + j], acc[j]);
            acc[j] = fmaf(v.w, wc[27 + j], acc[j]);
          }
        }
      }
      // butterfly reduce over the 16-lane group
#pragma unroll
      for (int d = 1; d < 16; d <<= 1) {
#pragma unroll
        for (int j = 0; j < 9; ++j) acc[j] += __shfl_xor(acc[j], d);
      }
      if (sub == 0) {
#pragma unroll
        for (int j = 0; j < 9; ++j)
          atomicAdd(&accum[(size_t)j * HW + vcell], acc[j]);
      }
    }
  }
}

// attention = sigmoid(sbb + sum over valid taps (bconst[j] + accum[j][q]));
// accum is 2.76 MB -> L2-resident reads.
__global__ __launch_bounds__(256) void conv_sig_kernel(
    const float* __restrict__ accum, const float* __restrict__ bconst,
    const float* __restrict__ sbb, const float* __restrict__ seg,
    float* __restrict__ sa) {
  int p = blockIdx.x * blockDim.x + threadIdx.x;  // exact 76800
  int y = p / W, x = p - y * W;
  float s = sbb[0];
#pragma unroll
  for (int dy = -1; dy <= 1; ++dy) {
#pragma unroll
    for (int dx = -1; dx <= 1; ++dx) {
      int yy = y + dy, xx = x + dx;
      if ((unsigned)yy < H && (unsigned)xx < W) {
        int j = (dy + 1) * 3 + (dx + 1);
        int q = yy * W + xx;
        s += bconst[j] + accum[(size_t)j * HW + q];
      }
    }
  }
  float att = 1.f / (1.f + expf(-s));
  sa[p] = att * seg[HW + p];
}

// out[c][p] = img[c][p] * sa[p]   (float4 over 19.66M elems)
__global__ __launch_bounds__(256) void final_mul_kernel(
    const float* __restrict__ img, const float* __restrict__ sa, float* __restrict__ out) {
  int i = blockIdx.x * blockDim.x + threadIdx.x;  // float4 index, exact 4915200
  int e = i * 4;
  int p = e % HW;  // 76800 % 4 == 0 so float4 stays within one channel row
  float4 v = *(const float4*)(img + e);
  float4 g = *(const float4*)(sa + p);
  float4 o = make_float4(v.x * g.x, v.y * g.y, v.z * g.z, v.w * g.w);
  *(float4*)(out + e) = o;
}

extern "C" void kernel_launch(void* const* d_in, const int* in_sizes, int n_in,
                              void* d_out, int out_size, void* d_ws, size_t ws_size,
                              hipStream_t stream) {
  const float* img = (const float*)d_in[0];
  const float* seg = (const float*)d_in[1];
  int iV0 = 2, iG0 = 3, iV1 = 4, iG1 = 5, iV2 = 6, iG2 = 7;
  if (in_sizes[3] != 2 * NPTS) {  // grouped (reference-arg) order fallback
    iV0 = 2; iV1 = 3; iV2 = 4; iG0 = 5; iG1 = 6; iG2 = 7;
  }
  const float* vf0 = (const float*)d_in[iV0];
  const float* vf1 = (const float*)d_in[iV1];
  const float* vf2 = (const float*)d_in[iV2];
  const int2* g0 = (const int2*)d_in[iG0];
  const int2* g1 = (const int2*)d_in[iG1];
  const int2* g2 = (const int2*)d_in[iG2];
  const float* rw0 = (const float*)d_in[8];
  const float* rb0 = (const float*)d_in[9];
  const float* rw1 = (const float*)d_in[10];
  const float* rb1 = (const float*)d_in[11];
  const float* sbw = (const float*)d_in[12];
  const float* sbb = (const float*)d_in[13];

  char* ws = (char*)d_ws;
  int* w0m = (int*)(ws + 0);
  int* w1m = (int*)(ws + OFF_W1M);
  int* w2m = (int*)(ws + OFF_W2M);
  float* accum = (float*)(ws + OFF_ACC);
  float* Weff0 = (float*)(ws + OFF_WE0);
  float* Weff1 = (float*)(ws + OFF_WE1);
  float* bconst = (float*)(ws + OFF_BC);
  float* sa = (float*)(ws + 0);  // aliases winner maps (dead after fused_t9)

  float* out = (float*)d_out;

  hipMemsetAsync(w0m, 0xFF, 3 * 307200, stream);   // winners = -1
  hipMemsetAsync(accum, 0, 9 * HW * 4, stream);    // tap accumulator = 0
  prep_and_scatter<<<7 + (NPTS + 255) / 256, 256, 0, stream>>>(
      rw0, rw1, rb0, rb1, sbw, Weff0, Weff1, bconst, g0, g1, g2, w0m, w1m, w2m);
  dim3 tg((NPTS + 255) / 256, 5);  // 469 x 5; img units self-guard at 300
  fused_t9<<<tg, 256, 0, stream>>>(img, seg, vf0, vf1, vf2, g0, g1, g2,
                                   w0m, w1m, w2m, Weff0, Weff1, sbw, accum);
  conv_sig_kernel<<<HW / 256, 256, 0, stream>>>(accum, bconst, sbb, seg, sa);
  final_mul_kernel<<<(out_size / 4) / 256, 256, 0, stream>>>(img, sa, out);
}